// Round 8
// baseline (193.506 us; speedup 1.0000x reference)
//
#include <hip/hip_runtime.h>

#define T_LEN 1024
#define NH 8
#define DH 64
#define CCH 512
#define LOG2E 1.44269504088896340736f

typedef _Float16 f16;
typedef _Float16 f16x8 __attribute__((ext_vector_type(8)));
typedef _Float16 f16x4 __attribute__((ext_vector_type(4)));
typedef float f32x4 __attribute__((ext_vector_type(4)));

// async global->LDS DMA, 16B per lane. LDS dest must equal wave-uniform base + lane*16.
__device__ __forceinline__ void dma16(const void* g, void* l)
{
    __builtin_amdgcn_global_load_lds((const __attribute__((address_space(1))) void*)g,
                                     (__attribute__((address_space(3))) void*)l, 16, 0, 0);
}

// ---------------------------------------------------------------------------
// prep: fused [transpose+cvt x -> xT fp16 [b*t][c]] and [W fp32 -> fp16].
// grid(16, 8, 3B + 8), block 256. (unchanged)
// ---------------------------------------------------------------------------
__global__ __launch_bounds__(256)
void prep_kernel(const float* __restrict__ x0, const float* __restrict__ x1,
                 const float* __restrict__ x2, const float* __restrict__ W0,
                 const float* __restrict__ W1, const float* __restrict__ W2,
                 const float* __restrict__ W3, f16* __restrict__ o0,
                 f16* __restrict__ o1, f16* __restrict__ o2, f16* __restrict__ w0,
                 f16* __restrict__ w1, f16* __restrict__ w2, f16* __restrict__ w3,
                 int B)
{
    const int z = blockIdx.z;
    if (z < 3 * B) {
        const int t0 = blockIdx.x * 64, c0 = blockIdx.y * 64;
        const int which = z / B, b = z % B;
        const float* x = (which == 0) ? x0 : (which == 1) ? x1 : x2;
        f16* o = (which == 0) ? o0 : (which == 1) ? o1 : o2;

        __shared__ float L[64 * 68];
        const int cl = threadIdx.x & 63, g = threadIdx.x >> 6;
        const float* src = x + ((size_t)(b * CCH + c0 + cl)) * T_LEN + t0 + g * 16;
        #pragma unroll
        for (int j = 0; j < 4; ++j)
            *(float4*)&L[cl * 68 + g * 16 + 4 * j] = *(const float4*)&src[4 * j];
        __syncthreads();
        const int tl = threadIdx.x & 63, cg = (threadIdx.x >> 6) * 16;
        f16 h[16];
        #pragma unroll
        for (int j = 0; j < 16; ++j) h[j] = (f16)L[(cg + j) * 68 + tl];
        f16* dst = o + ((size_t)(b * T_LEN + t0 + tl)) * CCH + c0 + cg;
        *(f16x8*)&dst[0] = *(f16x8*)&h[0];
        *(f16x8*)&dst[8] = *(f16x8*)&h[8];
    } else {
        const int slice = z - 3 * B;
        size_t i = ((size_t)(slice * 128 + blockIdx.y * 16 + blockIdx.x) * 256 + threadIdx.x) * 4;
        const int wi = (int)(i >> 18);
        const size_t off = i & 262143;
        const float* src = (wi == 0) ? W0 : (wi == 1) ? W1 : (wi == 2) ? W2 : W3;
        f16* dst = (wi == 0) ? w0 : (wi == 1) ? w1 : (wi == 2) ? w2 : w3;
        float4 v4 = *(const float4*)&src[off];
        f16x4 h = {(f16)v4.x, (f16)v4.y, (f16)v4.z, (f16)v4.w};
        *(f16x4*)&dst[off] = h;
    }
}

// ---------------------------------------------------------------------------
// q/k/v projection 64(r) x 128(o), BK=128. grid(B*16, 4, 3), block 256,
// 48 KB LDS -> 3 blocks/CU. (unchanged)
// ---------------------------------------------------------------------------
__global__ __launch_bounds__(256)
void proj_qkv(const f16* __restrict__ xq, const f16* __restrict__ xk,
              const f16* __restrict__ xv, const f16* __restrict__ wq,
              const f16* __restrict__ wk, const f16* __restrict__ wv,
              const float* __restrict__ bq, const float* __restrict__ bk,
              const float* __restrict__ bv, f16* __restrict__ qo,
              f16* __restrict__ ko, f16* __restrict__ vo)
{
    const int which = blockIdx.z;
    const f16* X = (which == 0) ? xq : (which == 1) ? xk : xv;
    const f16* W = (which == 0) ? wq : (which == 1) ? wk : wv;
    const float* bias = (which == 0) ? bq : (which == 1) ? bk : bv;
    const float scale = (which == 0) ? 0.125f * LOG2E : 1.0f;

    const int r0 = blockIdx.x * 64;    // flat (b,t)
    const int o0 = blockIdx.y * 128;   // out channel
    const int tid = threadIdx.x;
    const int w = tid >> 6, lane = tid & 63;
    const int quad = lane >> 4, l15 = lane & 15;

    __shared__ __align__(16) f16 Xs[64 * 128];    // 16 KB
    __shared__ __align__(16) f16 Wsh[128 * 128];  // 32 KB

    const int srow = tid >> 4;                    // 0..15 (+16/pass)
    const int scol = ((tid & 15) ^ srow) << 3;    // pre-swizzled global col

    const f16* Xg = X + (size_t)(r0 + srow) * CCH + scol;
    const f16* Wg = W + (size_t)(o0 + srow) * CCH + scol;

    const int ax = (which < 2) ? (w >> 1) : (w & 1);
    const int aw = (which < 2) ? (w & 1) : (w >> 1);

    f32x4 acc[8] = {};

    for (int kc = 0; kc < 4; ++kc) {
        if (kc) __syncthreads();
        const int c1 = kc * 128;
        #pragma unroll
        for (int jj = 0; jj < 8; ++jj)
            dma16(Wg + c1 + (size_t)(16 * jj) * CCH, &Wsh[((size_t)tid + 256 * jj) * 8]);
        #pragma unroll
        for (int jj = 0; jj < 4; ++jj)
            dma16(Xg + c1 + (size_t)(16 * jj) * CCH, &Xs[((size_t)tid + 256 * jj) * 8]);
        __syncthreads();

        #pragma unroll
        for (int ks = 0; ks < 4; ++ks) {
            const int sl = ((ks * 4 + quad) ^ l15) << 3;
            f16x8 xf[2], wf[4];
            #pragma unroll
            for (int i = 0; i < 2; ++i)
                xf[i] = *(const f16x8*)&Xs[(32 * ax + 16 * i + l15) * 128 + sl];
            #pragma unroll
            for (int j = 0; j < 4; ++j)
                wf[j] = *(const f16x8*)&Wsh[(64 * aw + 16 * j + l15) * 128 + sl];
            if (which < 2) {
                #pragma unroll
                for (int i = 0; i < 2; ++i)
                    #pragma unroll
                    for (int j = 0; j < 4; ++j)
                        acc[i * 4 + j] = __builtin_amdgcn_mfma_f32_16x16x32_f16(
                            xf[i], wf[j], acc[i * 4 + j], 0, 0, 0);
            } else {
                #pragma unroll
                for (int i = 0; i < 4; ++i)
                    #pragma unroll
                    for (int j = 0; j < 2; ++j)
                        acc[i * 2 + j] = __builtin_amdgcn_mfma_f32_16x16x32_f16(
                            wf[i], xf[j], acc[i * 2 + j], 0, 0, 0);
            }
        }
    }

    if (which < 2) {
        f16* out = (which == 0) ? qo : ko;
        float bl[4];
        #pragma unroll
        for (int j = 0; j < 4; ++j) bl[j] = bias[o0 + 64 * aw + 16 * j + l15];
        #pragma unroll
        for (int i = 0; i < 2; ++i)
            #pragma unroll
            for (int r = 0; r < 4; ++r) {
                size_t row = (size_t)(r0 + 32 * ax + 16 * i + 4 * quad + r) * CCH;
                #pragma unroll
                for (int j = 0; j < 4; ++j)
                    out[row + o0 + 64 * aw + 16 * j + l15] =
                        (f16)((acc[i * 4 + j][r] + bl[j]) * scale);
            }
    } else {
        const int bb = r0 >> 10, tb = r0 & 1023;
        #pragma unroll
        for (int i = 0; i < 4; ++i) {
            float4 bv4 = *(const float4*)&bias[o0 + 64 * aw + 16 * i + 4 * quad];
            float bl[4] = {bv4.x, bv4.y, bv4.z, bv4.w};
            #pragma unroll
            for (int r = 0; r < 4; ++r) {
                size_t row = ((size_t)(bb * CCH + o0 + 64 * aw + 16 * i + 4 * quad + r)) * T_LEN;
                #pragma unroll
                for (int j = 0; j < 2; ++j)
                    vo[row + tb + 32 * ax + 16 * j + l15] =
                        (f16)(acc[i * 2 + j][r] + bl[r]);
            }
        }
    }
}

// ---------------------------------------------------------------------------
// MFMA flash attention: single-group grid restored (512 blocks, 4 waves/SIMD)
// + rel-v band term converted from ~144 scalar FMAs/wave to ONE MFMA path:
// lanes predicated-write in-band P values into Pbs[sw][64][40] (col j = s-t+4,
// k 0..31 zeroed, 16B-aligned rows), then ds_read_b128 + 4x mfma against a
// prologue-hoisted zero-padded evb B-fragment. VALU cut ~20% (R7 counters:
// VALUBusy 30% @2w/SIMD, MfmaUtil 6.6% -> VALU-limited at 4w/SIMD).
// 63 KB LDS -> 2 blocks/CU. grid(16*NH*B), block 512.
// ---------------------------------------------------------------------------
__global__ __launch_bounds__(512, 4)
void attn_mfma(const f16* __restrict__ q, const f16* __restrict__ kk,
               const f16* __restrict__ v, const float* __restrict__ ekg,
               const float* __restrict__ evg, f16* __restrict__ ctx)
{
    const int G = gridDim.x >> 4;                  // NH*B groups
    const int grp = blockIdx.x % G;                // (b,h) group -> XCD grp%8
    const int ib = blockIdx.x / G;                 // t-block 0..15
    const int h = grp & 7, b = grp >> 3;
    const int t0 = ib * 64;
    const int tid = threadIdx.x;
    const int w = tid >> 6, lane = tid & 63;
    const int quad = lane >> 4, l15 = lane & 15;
    const int qw = w & 3, sw = w >> 2;

    __shared__ __align__(16) f16 Qs[4096], Ps[4096];
    __shared__ __align__(16) f16 KV[2][2][4096];   // [buf][0=K,1=V][64x64 swz]
    __shared__ __align__(16) f16 Pbs[2 * 64 * 40]; // band P tiles per sw, 10 KB
    __shared__ float eks[576], evs[576];
    __shared__ float lsp[2][64];

    const int srow = tid >> 3;                     // 0..63
    const int scol = ((tid & 7) ^ (srow & 7)) << 3;

    for (int i = tid; i < 576; i += 512) {
        eks[i] = ekg[h * 576 + i];
        evs[i] = evg[h * 576 + i];
    }

    const f16* gk = kk + ((size_t)(b * T_LEN + srow)) * CCH + h * DH + scol;
    const f16* gv = v + ((size_t)(b * CCH + h * DH + srow)) * T_LEN + scol;

    dma16(q + ((size_t)(b * T_LEN + t0 + srow)) * CCH + h * DH + scol, &Qs[(size_t)tid * 8]);
    dma16(gk, &KV[0][0][(size_t)tid * 8]);
    dma16(gv, &KV[0][1][(size_t)tid * 8]);
    __syncthreads();

    f16x8 qf[2];
    #pragma unroll
    for (int ks = 0; ks < 2; ++ks)
        qf[ks] = *(const f16x8*)&Qs[(16 * qw + l15) * 64 + (((ks * 4 + quad) ^ (l15 & 7)) << 3)];

    // hoisted B-fragment for the band MFMA: evb[ct][i] = evs[k=8*quad+i][16ct+l15],
    // zero for k >= 9 (zero-padded K=32).
    f16x8 evb[4];
    #pragma unroll
    for (int ct = 0; ct < 4; ++ct)
        #pragma unroll
        for (int i = 0; i < 8; ++i) {
            int k = 8 * quad + i;
            evb[ct][i] = (k < 9) ? (f16)evs[k * 64 + 16 * ct + l15] : (f16)0.f;
        }

    const int myt = 16 * qw + l15;
    const int pbase = sw * 2560 + myt * 40;        // this lane's Pbs row
    float Ssum = 0.f;
    f32x4 O[4] = {};

    const bool corner_hi = (ib == 0);
    const bool corner_lo = (ib == 15);

    for (int it = 0; it < 16; ++it) {
        const int kb = it, cb = it & 1;
        const int s0g = kb * 64;
        const bool band = (s0g <= t0 + 67 && s0g + 63 >= t0 - 4);
        if (it) __syncthreads();

        if (it < 15) {
            const int nb = cb ^ 1;
            dma16(gk + (size_t)((it + 1) * 64) * CCH, &KV[nb][0][(size_t)tid * 8]);
            dma16(gv + (it + 1) * 64, &KV[nb][1][(size_t)tid * 8]);
        }

        f32x4 S[2] = {};
        __builtin_amdgcn_s_setprio(1);
        #pragma unroll
        for (int ks = 0; ks < 2; ++ks) {
            #pragma unroll
            for (int cti = 0; cti < 2; ++cti) {
                const int ct = 2 * sw + cti;
                f16x8 aa = *(const f16x8*)&KV[cb][0][(16 * ct + l15) * 64 +
                                                     (((ks * 4 + quad) ^ (l15 & 7)) << 3)];
                S[cti] = __builtin_amdgcn_mfma_f32_16x16x32_f16(aa, qf[ks], S[cti], 0, 0, 0);
            }
        }
        __builtin_amdgcn_s_setprio(0);

        if ((corner_hi && kb == 15) || (corner_lo && kb == 0)) {
            #pragma unroll
            for (int cti = 0; cti < 2; ++cti) {
                const int ct = 2 * sw + cti;
                #pragma unroll
                for (int r = 0; r < 4; ++r) {
                    int t_g = t0 + myt;
                    int s_g = s0g + 16 * ct + 4 * quad + r;
                    int df = s_g - t_g;
                    if (df >= 1019 && df <= 1023) {
                        const float* ekp = &eks[(df - 1019) * 64];
                        float sacc = 0.f;
                        for (int d = 0; d < 64; ++d)
                            sacc += (float)Qs[myt * 64 + (((d >> 3) ^ (myt & 7)) << 3) + (d & 7)] * ekp[d];
                        S[cti][r] += sacc;
                    } else if (df >= -1023 && df <= -1021) {
                        const float* ekp = &eks[(1029 + df) * 64];
                        const int t2 = myt - 1;
                        float sacc = 0.f;
                        for (int d = 0; d < 64; ++d)
                            sacc += (float)Qs[t2 * 64 + (((d >> 3) ^ (t2 & 7)) << 3) + (d & 7)] * ekp[d];
                        S[cti][r] += sacc;
                    }
                }
            }
        }

        if (band) {                                // zero k 0..31 of this lane's row
            f16x8 z = {};
            *(f16x8*)&Pbs[pbase + 8 * quad] = z;
        }

        #pragma unroll
        for (int cti = 0; cti < 2; ++cti) {
            const int ct = 2 * sw + cti;
            f16x4 pk_;
            #pragma unroll
            for (int r = 0; r < 4; ++r) {
                float p = exp2f(S[cti][r]);
                Ssum += p;
                pk_[r] = (f16)p;
                if (band) {
                    int j = s0g + 16 * ct + 4 * quad + r - t0 - myt + 4;
                    if (j >= 0 && j <= 8) Pbs[pbase + j] = pk_[r];
                }
            }
            int colh = (((2 * ct + (quad >> 1)) ^ (myt & 7)) << 3) + (quad & 1) * 4;
            *(f16x4*)&Ps[myt * 64 + colh] = pk_;
        }
        // no barrier: Ps quarter / Pbs rows are wave-private.

        __builtin_amdgcn_s_setprio(1);
        {
            f16x8 aa = *(const f16x8*)&Ps[(16 * qw + l15) * 64 +
                                          (((sw * 4 + quad) ^ (l15 & 7)) << 3)];
            #pragma unroll
            for (int ct = 0; ct < 4; ++ct) {
                f16x8 bf = *(const f16x8*)&KV[cb][1][(16 * ct + l15) * 64 +
                                                     (((sw * 4 + quad) ^ (l15 & 7)) << 3)];
                O[ct] = __builtin_amdgcn_mfma_f32_16x16x32_f16(aa, bf, O[ct], 0, 0, 0);
            }
        }
        __builtin_amdgcn_s_setprio(0);

        if (band) {                                // banded rel-v term as one MFMA set
            f16x8 pb = *(const f16x8*)&Pbs[sw * 2560 + (16 * qw + l15) * 40 + 8 * quad];
            #pragma unroll
            for (int ct = 0; ct < 4; ++ct)
                O[ct] = __builtin_amdgcn_mfma_f32_16x16x32_f16(pb, evb[ct], O[ct], 0, 0, 0);
        }
    }

    // ---- cross-sw reduction ----
    Ssum += __shfl_xor(Ssum, 16);
    Ssum += __shfl_xor(Ssum, 32);
    if (quad == 0) lsp[sw][myt] = Ssum;
    __syncthreads();                       // all K/V reads done; lsp visible

    float* Ored = (float*)&KV[0][0][0];    // 64 rows x stride 66 = 16.9 KB
    if (sw == 1) {
        #pragma unroll
        for (int r = 0; r < 4; ++r) {
            const int t_loc = 16 * qw + 4 * quad + r;
            #pragma unroll
            for (int ct = 0; ct < 4; ++ct)
                Ored[t_loc * 66 + 16 * ct + l15] = O[ct][r];
        }
    }
    __syncthreads();

    if (sw == 0) {
        #pragma unroll
        for (int r = 0; r < 4; ++r) {
            const int t_loc = 16 * qw + 4 * quad + r;
            const float rl = 1.0f / (lsp[0][t_loc] + lsp[1][t_loc]);
            size_t rowo = ((size_t)(b * T_LEN + t0 + t_loc)) * CCH + h * DH;
            #pragma unroll
            for (int ct = 0; ct < 4; ++ct)
                ctx[rowo + 16 * ct + l15] =
                    (f16)((O[ct][r] + Ored[t_loc * 66 + 16 * ct + l15]) * rl);
        }
    }
}

// ---------------------------------------------------------------------------
// output projection 64(o) x 64(t), BK=128. grid(B*16, 8), block 256,
// 32 KB LDS -> 2 blocks/CU. (unchanged)
// ---------------------------------------------------------------------------
__global__ __launch_bounds__(256)
void proj_out(const f16* __restrict__ ctx, const f16* __restrict__ Wo,
              const float* __restrict__ bo, float* __restrict__ out)
{
    const int r0 = blockIdx.x * 64;    // flat (b,t)
    const int o0 = blockIdx.y * 64;
    const int tid = threadIdx.x;
    const int w = tid >> 6, lane = tid & 63;
    const int quad = lane >> 4, l15 = lane & 15;
    const int a  = w >> 1;   // o-half (32 rows)
    const int b2 = w & 1;    // t-half (32 cols)

    __shared__ __align__(16) f16 Cs[64 * 128];    // 16 KB
    __shared__ __align__(16) f16 Wsh[64 * 128];   // 16 KB

    const int srow = tid >> 4;                    // 0..15 (+16/pass)
    const int scol = ((tid & 15) ^ srow) << 3;

    const f16* Cg = ctx + (size_t)(r0 + srow) * CCH + scol;
    const f16* Wg = Wo + (size_t)(o0 + srow) * CCH + scol;

    f32x4 acc[2][2] = {};

    for (int kc = 0; kc < 4; ++kc) {
        if (kc) __syncthreads();
        const int c1 = kc * 128;
        #pragma unroll
        for (int jj = 0; jj < 4; ++jj) {
            dma16(Wg + c1 + (size_t)(16 * jj) * CCH, &Wsh[((size_t)tid + 256 * jj) * 8]);
            dma16(Cg + c1 + (size_t)(16 * jj) * CCH, &Cs[((size_t)tid + 256 * jj) * 8]);
        }
        __syncthreads();

        #pragma unroll
        for (int ks = 0; ks < 4; ++ks) {
            const int sl = ((ks * 4 + quad) ^ l15) << 3;
            f16x8 wf[2], cf[2];
            #pragma unroll
            for (int i = 0; i < 2; ++i)
                wf[i] = *(const f16x8*)&Wsh[(32 * a + 16 * i + l15) * 128 + sl];
            #pragma unroll
            for (int j = 0; j < 2; ++j)
                cf[j] = *(const f16x8*)&Cs[(32 * b2 + 16 * j + l15) * 128 + sl];
            #pragma unroll
            for (int i = 0; i < 2; ++i)
                #pragma unroll
                for (int j = 0; j < 2; ++j)
                    acc[i][j] = __builtin_amdgcn_mfma_f32_16x16x32_f16(
                        wf[i], cf[j], acc[i][j], 0, 0, 0);
        }
    }

    const int bb = r0 >> 10, tb = r0 & 1023;
    #pragma unroll
    for (int i = 0; i < 2; ++i) {
        float4 bv4 = *(const float4*)&bo[o0 + 32 * a + 16 * i + 4 * quad];
        float bl[4] = {bv4.x, bv4.y, bv4.z, bv4.w};
        #pragma unroll
        for (int r = 0; r < 4; ++r) {
            size_t row = ((size_t)(bb * CCH + o0 + 32 * a + 16 * i + 4 * quad + r)) * T_LEN;
            #pragma unroll
            for (int j = 0; j < 2; ++j)
                out[row + tb + 32 * b2 + 16 * j + l15] = acc[i][j][r] + bl[r];
        }
    }
}

// ---------------------------------------------------------------------------
extern "C" void kernel_launch(void* const* d_in, const int* in_sizes, int n_in,
                              void* d_out, int out_size, void* d_ws, size_t ws_size,
                              hipStream_t stream)
{
    const float* x_q = (const float*)d_in[0];
    const float* x_k = (const float*)d_in[1];
    const float* x_v = (const float*)d_in[2];
    const float* Wq  = (const float*)d_in[3];
    const float* bq  = (const float*)d_in[4];
    const float* Wk  = (const float*)d_in[5];
    const float* bk  = (const float*)d_in[6];
    const float* Wv  = (const float*)d_in[7];
    const float* bv  = (const float*)d_in[8];
    const float* Wo  = (const float*)d_in[9];
    const float* bo  = (const float*)d_in[10];
    const float* erk = (const float*)d_in[11];
    const float* erv = (const float*)d_in[12];

    const int B = in_sizes[0] / (CCH * T_LEN);
    const size_t te = (size_t)B * CCH * T_LEN;
    const size_t we = (size_t)CCH * CCH;

    f16* p = (f16*)d_ws;
    f16* xTq = p; p += te;
    f16* xTk = p; p += te;
    f16* xTv = p; p += te;
    f16* wqh = p; p += we;
    f16* wkh = p; p += we;
    f16* wvh = p; p += we;
    f16* woh = p; p += we;
    f16* qh  = p; p += te;
    f16* kh  = p; p += te;
    f16* vh  = p; p += te;
    f16* ch  = p; p += te;

    dim3 blk(256);
    prep_kernel<<<dim3(16, 8, 3 * B + 8), blk, 0, stream>>>(
        x_q, x_k, x_v, Wq, Wk, Wv, Wo, xTq, xTk, xTv, wqh, wkh, wvh, woh, B);
    proj_qkv<<<dim3(B * 16, 4, 3), blk, 0, stream>>>(
        xTq, xTk, xTv, wqh, wkh, wvh, bq, bk, bv, qh, kh, vh);
    attn_mfma<<<dim3(16 * NH * B), dim3(512), 0, stream>>>(
        qh, kh, vh, erk, erv, ch);
    proj_out<<<dim3(B * 16, 8), blk, 0, stream>>>(
        ch, woh, bo, (float*)d_out);
}

// Round 9
// 142.760 us; speedup vs baseline: 1.3555x; 1.3555x over previous
//
#include <hip/hip_runtime.h>

#define T_LEN 1024
#define NH 8
#define DH 64
#define CCH 512
#define LOG2E 1.44269504088896340736f

typedef _Float16 f16;
typedef _Float16 f16x8 __attribute__((ext_vector_type(8)));
typedef _Float16 f16x4 __attribute__((ext_vector_type(4)));
typedef float f32x4 __attribute__((ext_vector_type(4)));

// async global->LDS DMA, 16B per lane. LDS dest must equal wave-uniform base + lane*16.
__device__ __forceinline__ void dma16(const void* g, void* l)
{
    __builtin_amdgcn_global_load_lds((const __attribute__((address_space(1))) void*)g,
                                     (__attribute__((address_space(3))) void*)l, 16, 0, 0);
}

// ---------------------------------------------------------------------------
// prep: fused [transpose+cvt x -> xT fp16 [b*t][c]] and [W fp32 -> fp16].
// grid(16, 8, 3B + 8), block 256. (unchanged)
// ---------------------------------------------------------------------------
__global__ __launch_bounds__(256)
void prep_kernel(const float* __restrict__ x0, const float* __restrict__ x1,
                 const float* __restrict__ x2, const float* __restrict__ W0,
                 const float* __restrict__ W1, const float* __restrict__ W2,
                 const float* __restrict__ W3, f16* __restrict__ o0,
                 f16* __restrict__ o1, f16* __restrict__ o2, f16* __restrict__ w0,
                 f16* __restrict__ w1, f16* __restrict__ w2, f16* __restrict__ w3,
                 int B)
{
    const int z = blockIdx.z;
    if (z < 3 * B) {
        const int t0 = blockIdx.x * 64, c0 = blockIdx.y * 64;
        const int which = z / B, b = z % B;
        const float* x = (which == 0) ? x0 : (which == 1) ? x1 : x2;
        f16* o = (which == 0) ? o0 : (which == 1) ? o1 : o2;

        __shared__ float L[64 * 68];
        const int cl = threadIdx.x & 63, g = threadIdx.x >> 6;
        const float* src = x + ((size_t)(b * CCH + c0 + cl)) * T_LEN + t0 + g * 16;
        #pragma unroll
        for (int j = 0; j < 4; ++j)
            *(float4*)&L[cl * 68 + g * 16 + 4 * j] = *(const float4*)&src[4 * j];
        __syncthreads();
        const int tl = threadIdx.x & 63, cg = (threadIdx.x >> 6) * 16;
        f16 h[16];
        #pragma unroll
        for (int j = 0; j < 16; ++j) h[j] = (f16)L[(cg + j) * 68 + tl];
        f16* dst = o + ((size_t)(b * T_LEN + t0 + tl)) * CCH + c0 + cg;
        *(f16x8*)&dst[0] = *(f16x8*)&h[0];
        *(f16x8*)&dst[8] = *(f16x8*)&h[8];
    } else {
        const int slice = z - 3 * B;
        size_t i = ((size_t)(slice * 128 + blockIdx.y * 16 + blockIdx.x) * 256 + threadIdx.x) * 4;
        const int wi = (int)(i >> 18);
        const size_t off = i & 262143;
        const float* src = (wi == 0) ? W0 : (wi == 1) ? W1 : (wi == 2) ? W2 : W3;
        f16* dst = (wi == 0) ? w0 : (wi == 1) ? w1 : (wi == 2) ? w2 : w3;
        float4 v4 = *(const float4*)&src[off];
        f16x4 h = {(f16)v4.x, (f16)v4.y, (f16)v4.z, (f16)v4.w};
        *(f16x4*)&dst[off] = h;
    }
}

// ---------------------------------------------------------------------------
// q/k/v projection 64(r) x 128(o), BK=128. grid(B*16, 4, 3), block 256,
// 48 KB LDS -> 3 blocks/CU. (unchanged)
// ---------------------------------------------------------------------------
__global__ __launch_bounds__(256)
void proj_qkv(const f16* __restrict__ xq, const f16* __restrict__ xk,
              const f16* __restrict__ xv, const f16* __restrict__ wq,
              const f16* __restrict__ wk, const f16* __restrict__ wv,
              const float* __restrict__ bq, const float* __restrict__ bk,
              const float* __restrict__ bv, f16* __restrict__ qo,
              f16* __restrict__ ko, f16* __restrict__ vo)
{
    const int which = blockIdx.z;
    const f16* X = (which == 0) ? xq : (which == 1) ? xk : xv;
    const f16* W = (which == 0) ? wq : (which == 1) ? wk : wv;
    const float* bias = (which == 0) ? bq : (which == 1) ? bk : bv;
    const float scale = (which == 0) ? 0.125f * LOG2E : 1.0f;

    const int r0 = blockIdx.x * 64;    // flat (b,t)
    const int o0 = blockIdx.y * 128;   // out channel
    const int tid = threadIdx.x;
    const int w = tid >> 6, lane = tid & 63;
    const int quad = lane >> 4, l15 = lane & 15;

    __shared__ __align__(16) f16 Xs[64 * 128];    // 16 KB
    __shared__ __align__(16) f16 Wsh[128 * 128];  // 32 KB

    const int srow = tid >> 4;                    // 0..15 (+16/pass)
    const int scol = ((tid & 15) ^ srow) << 3;    // pre-swizzled global col

    const f16* Xg = X + (size_t)(r0 + srow) * CCH + scol;
    const f16* Wg = W + (size_t)(o0 + srow) * CCH + scol;

    const int ax = (which < 2) ? (w >> 1) : (w & 1);
    const int aw = (which < 2) ? (w & 1) : (w >> 1);

    f32x4 acc[8] = {};

    for (int kc = 0; kc < 4; ++kc) {
        if (kc) __syncthreads();
        const int c1 = kc * 128;
        #pragma unroll
        for (int jj = 0; jj < 8; ++jj)
            dma16(Wg + c1 + (size_t)(16 * jj) * CCH, &Wsh[((size_t)tid + 256 * jj) * 8]);
        #pragma unroll
        for (int jj = 0; jj < 4; ++jj)
            dma16(Xg + c1 + (size_t)(16 * jj) * CCH, &Xs[((size_t)tid + 256 * jj) * 8]);
        __syncthreads();

        #pragma unroll
        for (int ks = 0; ks < 4; ++ks) {
            const int sl = ((ks * 4 + quad) ^ l15) << 3;
            f16x8 xf[2], wf[4];
            #pragma unroll
            for (int i = 0; i < 2; ++i)
                xf[i] = *(const f16x8*)&Xs[(32 * ax + 16 * i + l15) * 128 + sl];
            #pragma unroll
            for (int j = 0; j < 4; ++j)
                wf[j] = *(const f16x8*)&Wsh[(64 * aw + 16 * j + l15) * 128 + sl];
            if (which < 2) {
                #pragma unroll
                for (int i = 0; i < 2; ++i)
                    #pragma unroll
                    for (int j = 0; j < 4; ++j)
                        acc[i * 4 + j] = __builtin_amdgcn_mfma_f32_16x16x32_f16(
                            xf[i], wf[j], acc[i * 4 + j], 0, 0, 0);
            } else {
                #pragma unroll
                for (int i = 0; i < 4; ++i)
                    #pragma unroll
                    for (int j = 0; j < 2; ++j)
                        acc[i * 2 + j] = __builtin_amdgcn_mfma_f32_16x16x32_f16(
                            wf[i], xf[j], acc[i * 2 + j], 0, 0, 0);
            }
        }
    }

    if (which < 2) {
        f16* out = (which == 0) ? qo : ko;
        float bl[4];
        #pragma unroll
        for (int j = 0; j < 4; ++j) bl[j] = bias[o0 + 64 * aw + 16 * j + l15];
        #pragma unroll
        for (int i = 0; i < 2; ++i)
            #pragma unroll
            for (int r = 0; r < 4; ++r) {
                size_t row = (size_t)(r0 + 32 * ax + 16 * i + 4 * quad + r) * CCH;
                #pragma unroll
                for (int j = 0; j < 4; ++j)
                    out[row + o0 + 64 * aw + 16 * j + l15] =
                        (f16)((acc[i * 4 + j][r] + bl[j]) * scale);
            }
    } else {
        const int bb = r0 >> 10, tb = r0 & 1023;
        #pragma unroll
        for (int i = 0; i < 4; ++i) {
            float4 bv4 = *(const float4*)&bias[o0 + 64 * aw + 16 * i + 4 * quad];
            float bl[4] = {bv4.x, bv4.y, bv4.z, bv4.w};
            #pragma unroll
            for (int r = 0; r < 4; ++r) {
                size_t row = ((size_t)(bb * CCH + o0 + 64 * aw + 16 * i + 4 * quad + r)) * T_LEN;
                #pragma unroll
                for (int j = 0; j < 2; ++j)
                    vo[row + tb + 32 * ax + 16 * j + l15] =
                        (f16)(acc[i * 2 + j][r] + bl[r]);
            }
        }
    }
}

// ---------------------------------------------------------------------------
// MFMA flash attention — R6 structure (8-wave split-s, dbuf K/V, wave-private
// Ps, scalar band loop, XCD-grouped 1-D grid) + ones-MFMA row-sum: the Ssum
// scalar adds (8 v_add/iter) and end shuffles fold into ONE extra
// mfma(aa, ones, Sacc) per iter on the idle MFMA pipe. Sacc's D-row mapping
// (t_loc = 16qw+4quad+r) matches the epilogue lsp index directly.
// Register delta vs R6: +7 VGPR (onesf 4 + Sacc 4 - Ssum 1) — half of R8's
// spilling edit; no new LDS. ~53 KB LDS, 2 blocks/CU, 4 waves/SIMD.
// grid(16*NH*B), block 512.
// ---------------------------------------------------------------------------
__global__ __launch_bounds__(512, 4)
void attn_mfma(const f16* __restrict__ q, const f16* __restrict__ kk,
               const f16* __restrict__ v, const float* __restrict__ ekg,
               const float* __restrict__ evg, f16* __restrict__ ctx)
{
    const int G = gridDim.x >> 4;                  // NH*B groups
    const int grp = blockIdx.x % G;                // (b,h) group -> XCD grp%8
    const int ib = blockIdx.x / G;                 // t-block 0..15
    const int h = grp & 7, b = grp >> 3;
    const int t0 = ib * 64;
    const int tid = threadIdx.x;
    const int w = tid >> 6, lane = tid & 63;
    const int quad = lane >> 4, l15 = lane & 15;
    const int qw = w & 3, sw = w >> 2;

    __shared__ __align__(16) f16 Qs[4096], Ps[4096];
    __shared__ __align__(16) f16 KV[2][2][4096];   // [buf][0=K,1=V][64x64 swz]
    __shared__ float eks[576], evs[576];
    __shared__ float lsp[2][64];

    const int srow = tid >> 3;                     // 0..63
    const int scol = ((tid & 7) ^ (srow & 7)) << 3;

    for (int i = tid; i < 576; i += 512) {
        eks[i] = ekg[h * 576 + i];
        evs[i] = evg[h * 576 + i];
    }

    const f16* gk = kk + ((size_t)(b * T_LEN + srow)) * CCH + h * DH + scol;
    const f16* gv = v + ((size_t)(b * CCH + h * DH + srow)) * T_LEN + scol;

    dma16(q + ((size_t)(b * T_LEN + t0 + srow)) * CCH + h * DH + scol, &Qs[(size_t)tid * 8]);
    dma16(gk, &KV[0][0][(size_t)tid * 8]);
    dma16(gv, &KV[0][1][(size_t)tid * 8]);
    __syncthreads();

    f16x8 qf[2];
    #pragma unroll
    for (int ks = 0; ks < 2; ++ks)
        qf[ks] = *(const f16x8*)&Qs[(16 * qw + l15) * 64 + (((ks * 4 + quad) ^ (l15 & 7)) << 3)];

    const f16 one_h = (f16)1.f;
    f16x8 onesf = {one_h, one_h, one_h, one_h, one_h, one_h, one_h, one_h};

    const int myt = 16 * qw + l15;
    f32x4 Sacc = {};                   // row-sum accum, rows t_loc=16qw+4quad+r
    f32x4 O[4] = {};

    const bool corner_hi = (ib == 0);
    const bool corner_lo = (ib == 15);

    for (int it = 0; it < 16; ++it) {
        const int kb = it, cb = it & 1;
        if (it) __syncthreads();

        if (it < 15) {
            const int nb = cb ^ 1;
            dma16(gk + (size_t)((it + 1) * 64) * CCH, &KV[nb][0][(size_t)tid * 8]);
            dma16(gv + (it + 1) * 64, &KV[nb][1][(size_t)tid * 8]);
        }

        f32x4 S[2] = {};
        __builtin_amdgcn_s_setprio(1);
        #pragma unroll
        for (int ks = 0; ks < 2; ++ks) {
            #pragma unroll
            for (int cti = 0; cti < 2; ++cti) {
                const int ct = 2 * sw + cti;
                f16x8 aa = *(const f16x8*)&KV[cb][0][(16 * ct + l15) * 64 +
                                                     (((ks * 4 + quad) ^ (l15 & 7)) << 3)];
                S[cti] = __builtin_amdgcn_mfma_f32_16x16x32_f16(aa, qf[ks], S[cti], 0, 0, 0);
            }
        }
        __builtin_amdgcn_s_setprio(0);

        if ((corner_hi && kb == 15) || (corner_lo && kb == 0)) {
            const int s0g = kb * 64;
            #pragma unroll
            for (int cti = 0; cti < 2; ++cti) {
                const int ct = 2 * sw + cti;
                #pragma unroll
                for (int r = 0; r < 4; ++r) {
                    int t_g = t0 + myt;
                    int s_g = s0g + 16 * ct + 4 * quad + r;
                    int df = s_g - t_g;
                    if (df >= 1019 && df <= 1023) {
                        const float* ekp = &eks[(df - 1019) * 64];
                        float sacc = 0.f;
                        for (int d = 0; d < 64; ++d)
                            sacc += (float)Qs[myt * 64 + (((d >> 3) ^ (myt & 7)) << 3) + (d & 7)] * ekp[d];
                        S[cti][r] += sacc;
                    } else if (df >= -1023 && df <= -1021) {
                        const float* ekp = &eks[(1029 + df) * 64];
                        const int t2 = myt - 1;
                        float sacc = 0.f;
                        for (int d = 0; d < 64; ++d)
                            sacc += (float)Qs[t2 * 64 + (((d >> 3) ^ (t2 & 7)) << 3) + (d & 7)] * ekp[d];
                        S[cti][r] += sacc;
                    }
                }
            }
        }

        #pragma unroll
        for (int cti = 0; cti < 2; ++cti) {
            const int ct = 2 * sw + cti;
            f16x4 pk_;
            #pragma unroll
            for (int r = 0; r < 4; ++r)
                pk_[r] = (f16)exp2f(S[cti][r]);
            int colh = (((2 * ct + (quad >> 1)) ^ (myt & 7)) << 3) + (quad & 1) * 4;
            *(f16x4*)&Ps[myt * 64 + colh] = pk_;
        }
        // no barrier: Ps quarter (rows 16qw..+15, cols 32sw..+31) wave-private.

        __builtin_amdgcn_s_setprio(1);
        {
            f16x8 aa = *(const f16x8*)&Ps[(16 * qw + l15) * 64 +
                                          (((sw * 4 + quad) ^ (l15 & 7)) << 3)];
            #pragma unroll
            for (int ct = 0; ct < 4; ++ct) {
                f16x8 bf = *(const f16x8*)&KV[cb][1][(16 * ct + l15) * 64 +
                                                     (((sw * 4 + quad) ^ (l15 & 7)) << 3)];
                O[ct] = __builtin_amdgcn_mfma_f32_16x16x32_f16(aa, bf, O[ct], 0, 0, 0);
            }
            // row-sum on the MFMA pipe: B==1 -> every D col = sum_k P[row][k]
            Sacc = __builtin_amdgcn_mfma_f32_16x16x32_f16(aa, onesf, Sacc, 0, 0, 0);
        }
        __builtin_amdgcn_s_setprio(0);

        const int s0g = kb * 64;
        if (s0g <= t0 + 67 && s0g + 63 >= t0 - 4) {
            #pragma unroll
            for (int r = 0; r < 4; ++r) {
                int t_loc = 16 * qw + 4 * quad + r;
                int t_g = t0 + t_loc;
                int slo = max(max(s0g, t_g - 4), s0g + 32 * sw);
                int shi = min(min(s0g + 63, t_g + 4), s0g + 32 * sw + 31);
                for (int s = slo; s <= shi; ++s) {
                    int sl = s - s0g;
                    float p = (float)Ps[t_loc * 64 + (((sl >> 3) ^ (t_loc & 7)) << 3) + (sl & 7)];
                    const float* evp = &evs[(s - t_g + 4) * 64];
                    #pragma unroll
                    for (int ct = 0; ct < 4; ++ct)
                        O[ct][r] += p * evp[16 * ct + l15];
                }
            }
        }
    }

    // ---- cross-sw reduction ----
    if (l15 == 0) {
        #pragma unroll
        for (int r = 0; r < 4; ++r)
            lsp[sw][16 * qw + 4 * quad + r] = Sacc[r];
    }
    __syncthreads();                       // all K/V reads done; lsp visible

    float* Ored = (float*)&KV[0][0][0];    // 64 rows x stride 66 = 16.9 KB
    if (sw == 1) {
        #pragma unroll
        for (int r = 0; r < 4; ++r) {
            const int t_loc = 16 * qw + 4 * quad + r;
            #pragma unroll
            for (int ct = 0; ct < 4; ++ct)
                Ored[t_loc * 66 + 16 * ct + l15] = O[ct][r];
        }
    }
    __syncthreads();

    if (sw == 0) {
        #pragma unroll
        for (int r = 0; r < 4; ++r) {
            const int t_loc = 16 * qw + 4 * quad + r;
            const float rl = 1.0f / (lsp[0][t_loc] + lsp[1][t_loc]);
            size_t rowo = ((size_t)(b * T_LEN + t0 + t_loc)) * CCH + h * DH;
            #pragma unroll
            for (int ct = 0; ct < 4; ++ct)
                ctx[rowo + 16 * ct + l15] =
                    (f16)((O[ct][r] + Ored[t_loc * 66 + 16 * ct + l15]) * rl);
        }
    }
}

// ---------------------------------------------------------------------------
// output projection 64(o) x 64(t), BK=128. grid(B*16, 8), block 256,
// 32 KB LDS -> 2 blocks/CU. (unchanged)
// ---------------------------------------------------------------------------
__global__ __launch_bounds__(256)
void proj_out(const f16* __restrict__ ctx, const f16* __restrict__ Wo,
              const float* __restrict__ bo, float* __restrict__ out)
{
    const int r0 = blockIdx.x * 64;    // flat (b,t)
    const int o0 = blockIdx.y * 64;
    const int tid = threadIdx.x;
    const int w = tid >> 6, lane = tid & 63;
    const int quad = lane >> 4, l15 = lane & 15;
    const int a  = w >> 1;   // o-half (32 rows)
    const int b2 = w & 1;    // t-half (32 cols)

    __shared__ __align__(16) f16 Cs[64 * 128];    // 16 KB
    __shared__ __align__(16) f16 Wsh[64 * 128];   // 16 KB

    const int srow = tid >> 4;                    // 0..15 (+16/pass)
    const int scol = ((tid & 15) ^ srow) << 3;

    const f16* Cg = ctx + (size_t)(r0 + srow) * CCH + scol;
    const f16* Wg = Wo + (size_t)(o0 + srow) * CCH + scol;

    f32x4 acc[2][2] = {};

    for (int kc = 0; kc < 4; ++kc) {
        if (kc) __syncthreads();
        const int c1 = kc * 128;
        #pragma unroll
        for (int jj = 0; jj < 4; ++jj) {
            dma16(Wg + c1 + (size_t)(16 * jj) * CCH, &Wsh[((size_t)tid + 256 * jj) * 8]);
            dma16(Cg + c1 + (size_t)(16 * jj) * CCH, &Cs[((size_t)tid + 256 * jj) * 8]);
        }
        __syncthreads();

        #pragma unroll
        for (int ks = 0; ks < 4; ++ks) {
            const int sl = ((ks * 4 + quad) ^ l15) << 3;
            f16x8 wf[2], cf[2];
            #pragma unroll
            for (int i = 0; i < 2; ++i)
                wf[i] = *(const f16x8*)&Wsh[(32 * a + 16 * i + l15) * 128 + sl];
            #pragma unroll
            for (int j = 0; j < 2; ++j)
                cf[j] = *(const f16x8*)&Cs[(32 * b2 + 16 * j + l15) * 128 + sl];
            #pragma unroll
            for (int i = 0; i < 2; ++i)
                #pragma unroll
                for (int j = 0; j < 2; ++j)
                    acc[i][j] = __builtin_amdgcn_mfma_f32_16x16x32_f16(
                        wf[i], cf[j], acc[i][j], 0, 0, 0);
        }
    }

    const int bb = r0 >> 10, tb = r0 & 1023;
    #pragma unroll
    for (int i = 0; i < 2; ++i) {
        float4 bv4 = *(const float4*)&bo[o0 + 32 * a + 16 * i + 4 * quad];
        float bl[4] = {bv4.x, bv4.y, bv4.z, bv4.w};
        #pragma unroll
        for (int r = 0; r < 4; ++r) {
            size_t row = ((size_t)(bb * CCH + o0 + 32 * a + 16 * i + 4 * quad + r)) * T_LEN;
            #pragma unroll
            for (int j = 0; j < 2; ++j)
                out[row + tb + 32 * b2 + 16 * j + l15] = acc[i][j][r] + bl[r];
        }
    }
}

// ---------------------------------------------------------------------------
extern "C" void kernel_launch(void* const* d_in, const int* in_sizes, int n_in,
                              void* d_out, int out_size, void* d_ws, size_t ws_size,
                              hipStream_t stream)
{
    const float* x_q = (const float*)d_in[0];
    const float* x_k = (const float*)d_in[1];
    const float* x_v = (const float*)d_in[2];
    const float* Wq  = (const float*)d_in[3];
    const float* bq  = (const float*)d_in[4];
    const float* Wk  = (const float*)d_in[5];
    const float* bk  = (const float*)d_in[6];
    const float* Wv  = (const float*)d_in[7];
    const float* bv  = (const float*)d_in[8];
    const float* Wo  = (const float*)d_in[9];
    const float* bo  = (const float*)d_in[10];
    const float* erk = (const float*)d_in[11];
    const float* erv = (const float*)d_in[12];

    const int B = in_sizes[0] / (CCH * T_LEN);
    const size_t te = (size_t)B * CCH * T_LEN;
    const size_t we = (size_t)CCH * CCH;

    f16* p = (f16*)d_ws;
    f16* xTq = p; p += te;
    f16* xTk = p; p += te;
    f16* xTv = p; p += te;
    f16* wqh = p; p += we;
    f16* wkh = p; p += we;
    f16* wvh = p; p += we;
    f16* woh = p; p += we;
    f16* qh  = p; p += te;
    f16* kh  = p; p += te;
    f16* vh  = p; p += te;
    f16* ch  = p; p += te;

    dim3 blk(256);
    prep_kernel<<<dim3(16, 8, 3 * B + 8), blk, 0, stream>>>(
        x_q, x_k, x_v, Wq, Wk, Wv, Wo, xTq, xTk, xTv, wqh, wkh, wvh, woh, B);
    proj_qkv<<<dim3(B * 16, 4, 3), blk, 0, stream>>>(
        xTq, xTk, xTv, wqh, wkh, wvh, bq, bk, bv, qh, kh, vh);
    attn_mfma<<<dim3(16 * NH * B), dim3(512), 0, stream>>>(
        qh, kh, vh, erk, erv, ch);
    proj_out<<<dim3(B * 16, 8), blk, 0, stream>>>(
        ch, woh, bo, (float*)d_out);
}

// Round 11
// 140.041 us; speedup vs baseline: 1.3818x; 1.0194x over previous
//
#include <hip/hip_runtime.h>

#define T_LEN 1024
#define NH 8
#define DH 64
#define CCH 512
#define LOG2E 1.44269504088896340736f

typedef _Float16 f16;
typedef _Float16 f16x8 __attribute__((ext_vector_type(8)));
typedef _Float16 f16x4 __attribute__((ext_vector_type(4)));
typedef __fp16 h16x2 __attribute__((ext_vector_type(2)));   // cvt_pkrtz native type
typedef float f32x4 __attribute__((ext_vector_type(4)));

#if __has_builtin(__builtin_amdgcn_exp2f)
#define EXP2(x) __builtin_amdgcn_exp2f(x)
#else
#define EXP2(x) exp2f(x)
#endif

// async global->LDS DMA, 16B per lane. LDS dest must equal wave-uniform base + lane*16.
__device__ __forceinline__ void dma16(const void* g, void* l)
{
    __builtin_amdgcn_global_load_lds((const __attribute__((address_space(1))) void*)g,
                                     (__attribute__((address_space(3))) void*)l, 16, 0, 0);
}

// ---------------------------------------------------------------------------
// prep: fused [transpose+cvt x -> xT fp16 [b*t][c]] and [W fp32 -> fp16].
// grid(16, 8, 3B + 8), block 256. (unchanged)
// ---------------------------------------------------------------------------
__global__ __launch_bounds__(256)
void prep_kernel(const float* __restrict__ x0, const float* __restrict__ x1,
                 const float* __restrict__ x2, const float* __restrict__ W0,
                 const float* __restrict__ W1, const float* __restrict__ W2,
                 const float* __restrict__ W3, f16* __restrict__ o0,
                 f16* __restrict__ o1, f16* __restrict__ o2, f16* __restrict__ w0,
                 f16* __restrict__ w1, f16* __restrict__ w2, f16* __restrict__ w3,
                 int B)
{
    const int z = blockIdx.z;
    if (z < 3 * B) {
        const int t0 = blockIdx.x * 64, c0 = blockIdx.y * 64;
        const int which = z / B, b = z % B;
        const float* x = (which == 0) ? x0 : (which == 1) ? x1 : x2;
        f16* o = (which == 0) ? o0 : (which == 1) ? o1 : o2;

        __shared__ float L[64 * 68];
        const int cl = threadIdx.x & 63, g = threadIdx.x >> 6;
        const float* src = x + ((size_t)(b * CCH + c0 + cl)) * T_LEN + t0 + g * 16;
        #pragma unroll
        for (int j = 0; j < 4; ++j)
            *(float4*)&L[cl * 68 + g * 16 + 4 * j] = *(const float4*)&src[4 * j];
        __syncthreads();
        const int tl = threadIdx.x & 63, cg = (threadIdx.x >> 6) * 16;
        f16 h[16];
        #pragma unroll
        for (int j = 0; j < 16; ++j) h[j] = (f16)L[(cg + j) * 68 + tl];
        f16* dst = o + ((size_t)(b * T_LEN + t0 + tl)) * CCH + c0 + cg;
        *(f16x8*)&dst[0] = *(f16x8*)&h[0];
        *(f16x8*)&dst[8] = *(f16x8*)&h[8];
    } else {
        const int slice = z - 3 * B;
        size_t i = ((size_t)(slice * 128 + blockIdx.y * 16 + blockIdx.x) * 256 + threadIdx.x) * 4;
        const int wi = (int)(i >> 18);
        const size_t off = i & 262143;
        const float* src = (wi == 0) ? W0 : (wi == 1) ? W1 : (wi == 2) ? W2 : W3;
        f16* dst = (wi == 0) ? w0 : (wi == 1) ? w1 : (wi == 2) ? w2 : w3;
        float4 v4 = *(const float4*)&src[off];
        f16x4 h = {(f16)v4.x, (f16)v4.y, (f16)v4.z, (f16)v4.w};
        *(f16x4*)&dst[off] = h;
    }
}

// ---------------------------------------------------------------------------
// q/k/v projection 64(r) x 128(o), BK=128. grid(B*16, 4, 3), block 256,
// 48 KB LDS -> 3 blocks/CU. (unchanged)
// ---------------------------------------------------------------------------
__global__ __launch_bounds__(256)
void proj_qkv(const f16* __restrict__ xq, const f16* __restrict__ xk,
              const f16* __restrict__ xv, const f16* __restrict__ wq,
              const f16* __restrict__ wk, const f16* __restrict__ wv,
              const float* __restrict__ bq, const float* __restrict__ bk,
              const float* __restrict__ bv, f16* __restrict__ qo,
              f16* __restrict__ ko, f16* __restrict__ vo)
{
    const int which = blockIdx.z;
    const f16* X = (which == 0) ? xq : (which == 1) ? xk : xv;
    const f16* W = (which == 0) ? wq : (which == 1) ? wk : wv;
    const float* bias = (which == 0) ? bq : (which == 1) ? bk : bv;
    const float scale = (which == 0) ? 0.125f * LOG2E : 1.0f;

    const int r0 = blockIdx.x * 64;    // flat (b,t)
    const int o0 = blockIdx.y * 128;   // out channel
    const int tid = threadIdx.x;
    const int w = tid >> 6, lane = tid & 63;
    const int quad = lane >> 4, l15 = lane & 15;

    __shared__ __align__(16) f16 Xs[64 * 128];    // 16 KB
    __shared__ __align__(16) f16 Wsh[128 * 128];  // 32 KB

    const int srow = tid >> 4;                    // 0..15 (+16/pass)
    const int scol = ((tid & 15) ^ srow) << 3;    // pre-swizzled global col

    const f16* Xg = X + (size_t)(r0 + srow) * CCH + scol;
    const f16* Wg = W + (size_t)(o0 + srow) * CCH + scol;

    const int ax = (which < 2) ? (w >> 1) : (w & 1);
    const int aw = (which < 2) ? (w & 1) : (w >> 1);

    f32x4 acc[8] = {};

    for (int kc = 0; kc < 4; ++kc) {
        if (kc) __syncthreads();
        const int c1 = kc * 128;
        #pragma unroll
        for (int jj = 0; jj < 8; ++jj)
            dma16(Wg + c1 + (size_t)(16 * jj) * CCH, &Wsh[((size_t)tid + 256 * jj) * 8]);
        #pragma unroll
        for (int jj = 0; jj < 4; ++jj)
            dma16(Xg + c1 + (size_t)(16 * jj) * CCH, &Xs[((size_t)tid + 256 * jj) * 8]);
        __syncthreads();

        #pragma unroll
        for (int ks = 0; ks < 4; ++ks) {
            const int sl = ((ks * 4 + quad) ^ l15) << 3;
            f16x8 xf[2], wf[4];
            #pragma unroll
            for (int i = 0; i < 2; ++i)
                xf[i] = *(const f16x8*)&Xs[(32 * ax + 16 * i + l15) * 128 + sl];
            #pragma unroll
            for (int j = 0; j < 4; ++j)
                wf[j] = *(const f16x8*)&Wsh[(64 * aw + 16 * j + l15) * 128 + sl];
            if (which < 2) {
                #pragma unroll
                for (int i = 0; i < 2; ++i)
                    #pragma unroll
                    for (int j = 0; j < 4; ++j)
                        acc[i * 4 + j] = __builtin_amdgcn_mfma_f32_16x16x32_f16(
                            xf[i], wf[j], acc[i * 4 + j], 0, 0, 0);
            } else {
                #pragma unroll
                for (int i = 0; i < 4; ++i)
                    #pragma unroll
                    for (int j = 0; j < 2; ++j)
                        acc[i * 2 + j] = __builtin_amdgcn_mfma_f32_16x16x32_f16(
                            wf[i], xf[j], acc[i * 2 + j], 0, 0, 0);
            }
        }
    }

    if (which < 2) {
        f16* out = (which == 0) ? qo : ko;
        float bl[4];
        #pragma unroll
        for (int j = 0; j < 4; ++j) bl[j] = bias[o0 + 64 * aw + 16 * j + l15];
        #pragma unroll
        for (int i = 0; i < 2; ++i)
            #pragma unroll
            for (int r = 0; r < 4; ++r) {
                size_t row = (size_t)(r0 + 32 * ax + 16 * i + 4 * quad + r) * CCH;
                #pragma unroll
                for (int j = 0; j < 4; ++j)
                    out[row + o0 + 64 * aw + 16 * j + l15] =
                        (f16)((acc[i * 4 + j][r] + bl[j]) * scale);
            }
    } else {
        const int bb = r0 >> 10, tb = r0 & 1023;
        #pragma unroll
        for (int i = 0; i < 4; ++i) {
            float4 bv4 = *(const float4*)&bias[o0 + 64 * aw + 16 * i + 4 * quad];
            float bl[4] = {bv4.x, bv4.y, bv4.z, bv4.w};
            #pragma unroll
            for (int r = 0; r < 4; ++r) {
                size_t row = ((size_t)(bb * CCH + o0 + 64 * aw + 16 * i + 4 * quad + r)) * T_LEN;
                #pragma unroll
                for (int j = 0; j < 2; ++j)
                    vo[row + tb + 32 * ax + 16 * j + l15] =
                        (f16)(acc[i * 2 + j][r] + bl[r]);
            }
        }
    }
}

// ---------------------------------------------------------------------------
// MFMA flash attention — R9 structure (8-wave split-s, dbuf K/V, wave-private
// Ps, ones-MFMA row-sum, XCD-grouped 1-D grid) + VALU diet:
//   * exp2f -> __builtin_amdgcn_exp2f (raw v_exp_f32; ocml wrapper adds
//     ~6-10 VALU/call incl. range clamping — S is bounded, clamp unneeded)
//   * f32->f16 via cvt_pkrtz packed pairs (4 ops vs 8 scalar cvt); result
//     received in the builtin's native __fp16x2 type (R10 compile fix)
//   * colh store addresses explicitly hoisted (loop-invariant)
// Register-neutral. ~53 KB LDS, 2 blocks/CU, 4 waves/SIMD.
// grid(16*NH*B), block 512.
// ---------------------------------------------------------------------------
__global__ __launch_bounds__(512, 4)
void attn_mfma(const f16* __restrict__ q, const f16* __restrict__ kk,
               const f16* __restrict__ v, const float* __restrict__ ekg,
               const float* __restrict__ evg, f16* __restrict__ ctx)
{
    const int G = gridDim.x >> 4;                  // NH*B groups
    const int grp = blockIdx.x % G;                // (b,h) group -> XCD grp%8
    const int ib = blockIdx.x / G;                 // t-block 0..15
    const int h = grp & 7, b = grp >> 3;
    const int t0 = ib * 64;
    const int tid = threadIdx.x;
    const int w = tid >> 6, lane = tid & 63;
    const int quad = lane >> 4, l15 = lane & 15;
    const int qw = w & 3, sw = w >> 2;

    __shared__ __align__(16) f16 Qs[4096], Ps[4096];
    __shared__ __align__(16) f16 KV[2][2][4096];   // [buf][0=K,1=V][64x64 swz]
    __shared__ float eks[576], evs[576];
    __shared__ float lsp[2][64];

    const int srow = tid >> 3;                     // 0..63
    const int scol = ((tid & 7) ^ (srow & 7)) << 3;

    for (int i = tid; i < 576; i += 512) {
        eks[i] = ekg[h * 576 + i];
        evs[i] = evg[h * 576 + i];
    }

    const f16* gk = kk + ((size_t)(b * T_LEN + srow)) * CCH + h * DH + scol;
    const f16* gv = v + ((size_t)(b * CCH + h * DH + srow)) * T_LEN + scol;

    dma16(q + ((size_t)(b * T_LEN + t0 + srow)) * CCH + h * DH + scol, &Qs[(size_t)tid * 8]);
    dma16(gk, &KV[0][0][(size_t)tid * 8]);
    dma16(gv, &KV[0][1][(size_t)tid * 8]);
    __syncthreads();

    f16x8 qf[2];
    #pragma unroll
    for (int ks = 0; ks < 2; ++ks)
        qf[ks] = *(const f16x8*)&Qs[(16 * qw + l15) * 64 + (((ks * 4 + quad) ^ (l15 & 7)) << 3)];

    const f16 one_h = (f16)1.f;
    f16x8 onesf = {one_h, one_h, one_h, one_h, one_h, one_h, one_h, one_h};

    const int myt = 16 * qw + l15;
    // loop-invariant Ps store addresses (ct = 2sw+cti -> 2*ct = 4sw+2cti)
    const int colh0 = (((4 * sw + (quad >> 1)) ^ (myt & 7)) << 3) + (quad & 1) * 4;
    const int colh1 = (((4 * sw + 2 + (quad >> 1)) ^ (myt & 7)) << 3) + (quad & 1) * 4;

    f32x4 Sacc = {};                   // row-sum accum, rows t_loc=16qw+4quad+r
    f32x4 O[4] = {};

    const bool corner_hi = (ib == 0);
    const bool corner_lo = (ib == 15);

    for (int it = 0; it < 16; ++it) {
        const int kb = it, cb = it & 1;
        if (it) __syncthreads();

        if (it < 15) {
            const int nb = cb ^ 1;
            dma16(gk + (size_t)((it + 1) * 64) * CCH, &KV[nb][0][(size_t)tid * 8]);
            dma16(gv + (it + 1) * 64, &KV[nb][1][(size_t)tid * 8]);
        }

        f32x4 S[2] = {};
        __builtin_amdgcn_s_setprio(1);
        #pragma unroll
        for (int ks = 0; ks < 2; ++ks) {
            #pragma unroll
            for (int cti = 0; cti < 2; ++cti) {
                const int ct = 2 * sw + cti;
                f16x8 aa = *(const f16x8*)&KV[cb][0][(16 * ct + l15) * 64 +
                                                     (((ks * 4 + quad) ^ (l15 & 7)) << 3)];
                S[cti] = __builtin_amdgcn_mfma_f32_16x16x32_f16(aa, qf[ks], S[cti], 0, 0, 0);
            }
        }
        __builtin_amdgcn_s_setprio(0);

        if ((corner_hi && kb == 15) || (corner_lo && kb == 0)) {
            const int s0g = kb * 64;
            #pragma unroll
            for (int cti = 0; cti < 2; ++cti) {
                const int ct = 2 * sw + cti;
                #pragma unroll
                for (int r = 0; r < 4; ++r) {
                    int t_g = t0 + myt;
                    int s_g = s0g + 16 * ct + 4 * quad + r;
                    int df = s_g - t_g;
                    if (df >= 1019 && df <= 1023) {
                        const float* ekp = &eks[(df - 1019) * 64];
                        float sacc = 0.f;
                        for (int d = 0; d < 64; ++d)
                            sacc += (float)Qs[myt * 64 + (((d >> 3) ^ (myt & 7)) << 3) + (d & 7)] * ekp[d];
                        S[cti][r] += sacc;
                    } else if (df >= -1023 && df <= -1021) {
                        const float* ekp = &eks[(1029 + df) * 64];
                        const int t2 = myt - 1;
                        float sacc = 0.f;
                        for (int d = 0; d < 64; ++d)
                            sacc += (float)Qs[t2 * 64 + (((d >> 3) ^ (t2 & 7)) << 3) + (d & 7)] * ekp[d];
                        S[cti][r] += sacc;
                    }
                }
            }
        }

        {
            // cti = 0
            h16x2 plo = __builtin_amdgcn_cvt_pkrtz(EXP2(S[0][0]), EXP2(S[0][1]));
            h16x2 phi = __builtin_amdgcn_cvt_pkrtz(EXP2(S[0][2]), EXP2(S[0][3]));
            f16x4 pk_;
            pk_[0] = (f16)plo[0]; pk_[1] = (f16)plo[1];
            pk_[2] = (f16)phi[0]; pk_[3] = (f16)phi[1];
            *(f16x4*)&Ps[myt * 64 + colh0] = pk_;
            // cti = 1
            plo = __builtin_amdgcn_cvt_pkrtz(EXP2(S[1][0]), EXP2(S[1][1]));
            phi = __builtin_amdgcn_cvt_pkrtz(EXP2(S[1][2]), EXP2(S[1][3]));
            pk_[0] = (f16)plo[0]; pk_[1] = (f16)plo[1];
            pk_[2] = (f16)phi[0]; pk_[3] = (f16)phi[1];
            *(f16x4*)&Ps[myt * 64 + colh1] = pk_;
        }
        // no barrier: Ps quarter (rows 16qw..+15, cols 32sw..+31) wave-private.

        __builtin_amdgcn_s_setprio(1);
        {
            f16x8 aa = *(const f16x8*)&Ps[(16 * qw + l15) * 64 +
                                          (((sw * 4 + quad) ^ (l15 & 7)) << 3)];
            #pragma unroll
            for (int ct = 0; ct < 4; ++ct) {
                f16x8 bf = *(const f16x8*)&KV[cb][1][(16 * ct + l15) * 64 +
                                                     (((sw * 4 + quad) ^ (l15 & 7)) << 3)];
                O[ct] = __builtin_amdgcn_mfma_f32_16x16x32_f16(aa, bf, O[ct], 0, 0, 0);
            }
            // row-sum on the MFMA pipe: B==1 -> every D col = sum_k P[row][k]
            Sacc = __builtin_amdgcn_mfma_f32_16x16x32_f16(aa, onesf, Sacc, 0, 0, 0);
        }
        __builtin_amdgcn_s_setprio(0);

        const int s0g = kb * 64;
        if (s0g <= t0 + 67 && s0g + 63 >= t0 - 4) {
            #pragma unroll
            for (int r = 0; r < 4; ++r) {
                int t_loc = 16 * qw + 4 * quad + r;
                int t_g = t0 + t_loc;
                int slo = max(max(s0g, t_g - 4), s0g + 32 * sw);
                int shi = min(min(s0g + 63, t_g + 4), s0g + 32 * sw + 31);
                for (int s = slo; s <= shi; ++s) {
                    int sl = s - s0g;
                    float p = (float)Ps[t_loc * 64 + (((sl >> 3) ^ (t_loc & 7)) << 3) + (sl & 7)];
                    const float* evp = &evs[(s - t_g + 4) * 64];
                    #pragma unroll
                    for (int ct = 0; ct < 4; ++ct)
                        O[ct][r] += p * evp[16 * ct + l15];
                }
            }
        }
    }

    // ---- cross-sw reduction ----
    if (l15 == 0) {
        #pragma unroll
        for (int r = 0; r < 4; ++r)
            lsp[sw][16 * qw + 4 * quad + r] = Sacc[r];
    }
    __syncthreads();                       // all K/V reads done; lsp visible

    float* Ored = (float*)&KV[0][0][0];    // 64 rows x stride 66 = 16.9 KB
    if (sw == 1) {
        #pragma unroll
        for (int r = 0; r < 4; ++r) {
            const int t_loc = 16 * qw + 4 * quad + r;
            #pragma unroll
            for (int ct = 0; ct < 4; ++ct)
                Ored[t_loc * 66 + 16 * ct + l15] = O[ct][r];
        }
    }
    __syncthreads();

    if (sw == 0) {
        #pragma unroll
        for (int r = 0; r < 4; ++r) {
            const int t_loc = 16 * qw + 4 * quad + r;
            const float rl = 1.0f / (lsp[0][t_loc] + lsp[1][t_loc]);
            size_t rowo = ((size_t)(b * T_LEN + t0 + t_loc)) * CCH + h * DH;
            #pragma unroll
            for (int ct = 0; ct < 4; ++ct)
                ctx[rowo + 16 * ct + l15] =
                    (f16)((O[ct][r] + Ored[t_loc * 66 + 16 * ct + l15]) * rl);
        }
    }
}

// ---------------------------------------------------------------------------
// output projection 64(o) x 64(t), BK=128. grid(B*16, 8), block 256,
// 32 KB LDS -> 2 blocks/CU. (unchanged)
// ---------------------------------------------------------------------------
__global__ __launch_bounds__(256)
void proj_out(const f16* __restrict__ ctx, const f16* __restrict__ Wo,
              const float* __restrict__ bo, float* __restrict__ out)
{
    const int r0 = blockIdx.x * 64;    // flat (b,t)
    const int o0 = blockIdx.y * 64;
    const int tid = threadIdx.x;
    const int w = tid >> 6, lane = tid & 63;
    const int quad = lane >> 4, l15 = lane & 15;
    const int a  = w >> 1;   // o-half (32 rows)
    const int b2 = w & 1;    // t-half (32 cols)

    __shared__ __align__(16) f16 Cs[64 * 128];    // 16 KB
    __shared__ __align__(16) f16 Wsh[64 * 128];   // 16 KB

    const int srow = tid >> 4;                    // 0..15 (+16/pass)
    const int scol = ((tid & 15) ^ srow) << 3;

    const f16* Cg = ctx + (size_t)(r0 + srow) * CCH + scol;
    const f16* Wg = Wo + (size_t)(o0 + srow) * CCH + scol;

    f32x4 acc[2][2] = {};

    for (int kc = 0; kc < 4; ++kc) {
        if (kc) __syncthreads();
        const int c1 = kc * 128;
        #pragma unroll
        for (int jj = 0; jj < 4; ++jj) {
            dma16(Wg + c1 + (size_t)(16 * jj) * CCH, &Wsh[((size_t)tid + 256 * jj) * 8]);
            dma16(Cg + c1 + (size_t)(16 * jj) * CCH, &Cs[((size_t)tid + 256 * jj) * 8]);
        }
        __syncthreads();

        #pragma unroll
        for (int ks = 0; ks < 4; ++ks) {
            const int sl = ((ks * 4 + quad) ^ l15) << 3;
            f16x8 wf[2], cf[2];
            #pragma unroll
            for (int i = 0; i < 2; ++i)
                wf[i] = *(const f16x8*)&Wsh[(32 * a + 16 * i + l15) * 128 + sl];
            #pragma unroll
            for (int j = 0; j < 2; ++j)
                cf[j] = *(const f16x8*)&Cs[(32 * b2 + 16 * j + l15) * 128 + sl];
            #pragma unroll
            for (int i = 0; i < 2; ++i)
                #pragma unroll
                for (int j = 0; j < 2; ++j)
                    acc[i][j] = __builtin_amdgcn_mfma_f32_16x16x32_f16(
                        wf[i], cf[j], acc[i][j], 0, 0, 0);
        }
    }

    const int bb = r0 >> 10, tb = r0 & 1023;
    #pragma unroll
    for (int i = 0; i < 2; ++i) {
        float4 bv4 = *(const float4*)&bo[o0 + 32 * a + 16 * i + 4 * quad];
        float bl[4] = {bv4.x, bv4.y, bv4.z, bv4.w};
        #pragma unroll
        for (int r = 0; r < 4; ++r) {
            size_t row = ((size_t)(bb * CCH + o0 + 32 * a + 16 * i + 4 * quad + r)) * T_LEN;
            #pragma unroll
            for (int j = 0; j < 2; ++j)
                out[row + tb + 32 * b2 + 16 * j + l15] = acc[i][j][r] + bl[r];
        }
    }
}

// ---------------------------------------------------------------------------
extern "C" void kernel_launch(void* const* d_in, const int* in_sizes, int n_in,
                              void* d_out, int out_size, void* d_ws, size_t ws_size,
                              hipStream_t stream)
{
    const float* x_q = (const float*)d_in[0];
    const float* x_k = (const float*)d_in[1];
    const float* x_v = (const float*)d_in[2];
    const float* Wq  = (const float*)d_in[3];
    const float* bq  = (const float*)d_in[4];
    const float* Wk  = (const float*)d_in[5];
    const float* bk  = (const float*)d_in[6];
    const float* Wv  = (const float*)d_in[7];
    const float* bv  = (const float*)d_in[8];
    const float* Wo  = (const float*)d_in[9];
    const float* bo  = (const float*)d_in[10];
    const float* erk = (const float*)d_in[11];
    const float* erv = (const float*)d_in[12];

    const int B = in_sizes[0] / (CCH * T_LEN);
    const size_t te = (size_t)B * CCH * T_LEN;
    const size_t we = (size_t)CCH * CCH;

    f16* p = (f16*)d_ws;
    f16* xTq = p; p += te;
    f16* xTk = p; p += te;
    f16* xTv = p; p += te;
    f16* wqh = p; p += we;
    f16* wkh = p; p += we;
    f16* wvh = p; p += we;
    f16* woh = p; p += we;
    f16* qh  = p; p += te;
    f16* kh  = p; p += te;
    f16* vh  = p; p += te;
    f16* ch  = p; p += te;

    dim3 blk(256);
    prep_kernel<<<dim3(16, 8, 3 * B + 8), blk, 0, stream>>>(
        x_q, x_k, x_v, Wq, Wk, Wv, Wo, xTq, xTk, xTv, wqh, wkh, wvh, woh, B);
    proj_qkv<<<dim3(B * 16, 4, 3), blk, 0, stream>>>(
        xTq, xTk, xTv, wqh, wkh, wvh, bq, bk, bv, qh, kh, vh);
    attn_mfma<<<dim3(16 * NH * B), dim3(512), 0, stream>>>(
        qh, kh, vh, erk, erv, ch);
    proj_out<<<dim3(B * 16, 8), blk, 0, stream>>>(
        ch, woh, bo, (float*)d_out);
}

// Round 12
// 139.163 us; speedup vs baseline: 1.3905x; 1.0063x over previous
//
#include <hip/hip_runtime.h>

#define T_LEN 1024
#define NH 8
#define DH 64
#define CCH 512
#define LOG2E 1.44269504088896340736f

typedef _Float16 f16;
typedef _Float16 f16x8 __attribute__((ext_vector_type(8)));
typedef _Float16 f16x4 __attribute__((ext_vector_type(4)));
typedef __fp16 h16x2 __attribute__((ext_vector_type(2)));   // cvt_pkrtz native type
typedef float f32x4 __attribute__((ext_vector_type(4)));

#if __has_builtin(__builtin_amdgcn_exp2f)
#define EXP2(x) __builtin_amdgcn_exp2f(x)
#else
#define EXP2(x) exp2f(x)
#endif

// async global->LDS DMA, 16B per lane. LDS dest must equal wave-uniform base + lane*16.
__device__ __forceinline__ void dma16(const void* g, void* l)
{
    __builtin_amdgcn_global_load_lds((const __attribute__((address_space(1))) void*)g,
                                     (__attribute__((address_space(3))) void*)l, 16, 0, 0);
}

// ---------------------------------------------------------------------------
// prep: fused [transpose+cvt x -> xT fp16 [b*t][c]] and [W fp32 -> fp16].
// grid(16, 8, 3B + 8), block 256. (unchanged)
// ---------------------------------------------------------------------------
__global__ __launch_bounds__(256)
void prep_kernel(const float* __restrict__ x0, const float* __restrict__ x1,
                 const float* __restrict__ x2, const float* __restrict__ W0,
                 const float* __restrict__ W1, const float* __restrict__ W2,
                 const float* __restrict__ W3, f16* __restrict__ o0,
                 f16* __restrict__ o1, f16* __restrict__ o2, f16* __restrict__ w0,
                 f16* __restrict__ w1, f16* __restrict__ w2, f16* __restrict__ w3,
                 int B)
{
    const int z = blockIdx.z;
    if (z < 3 * B) {
        const int t0 = blockIdx.x * 64, c0 = blockIdx.y * 64;
        const int which = z / B, b = z % B;
        const float* x = (which == 0) ? x0 : (which == 1) ? x1 : x2;
        f16* o = (which == 0) ? o0 : (which == 1) ? o1 : o2;

        __shared__ float L[64 * 68];
        const int cl = threadIdx.x & 63, g = threadIdx.x >> 6;
        const float* src = x + ((size_t)(b * CCH + c0 + cl)) * T_LEN + t0 + g * 16;
        #pragma unroll
        for (int j = 0; j < 4; ++j)
            *(float4*)&L[cl * 68 + g * 16 + 4 * j] = *(const float4*)&src[4 * j];
        __syncthreads();
        const int tl = threadIdx.x & 63, cg = (threadIdx.x >> 6) * 16;
        f16 h[16];
        #pragma unroll
        for (int j = 0; j < 16; ++j) h[j] = (f16)L[(cg + j) * 68 + tl];
        f16* dst = o + ((size_t)(b * T_LEN + t0 + tl)) * CCH + c0 + cg;
        *(f16x8*)&dst[0] = *(f16x8*)&h[0];
        *(f16x8*)&dst[8] = *(f16x8*)&h[8];
    } else {
        const int slice = z - 3 * B;
        size_t i = ((size_t)(slice * 128 + blockIdx.y * 16 + blockIdx.x) * 256 + threadIdx.x) * 4;
        const int wi = (int)(i >> 18);
        const size_t off = i & 262143;
        const float* src = (wi == 0) ? W0 : (wi == 1) ? W1 : (wi == 2) ? W2 : W3;
        f16* dst = (wi == 0) ? w0 : (wi == 1) ? w1 : (wi == 2) ? w2 : w3;
        float4 v4 = *(const float4*)&src[off];
        f16x4 h = {(f16)v4.x, (f16)v4.y, (f16)v4.z, (f16)v4.w};
        *(f16x4*)&dst[off] = h;
    }
}

// ---------------------------------------------------------------------------
// q/k/v projection 64(r) x 128(o), BK=128, XCD-aware 1-D grid: id%8 == r%8,
// so all 4 o-tiles x 3 tensors of one r-panel land on ONE XCD -> the X row
// panel (64x1KB) is L2-resident across its 12 consumers (per-XCD working set
// ~3 MB < 4 MB L2). Math identical to R11. grid(B*192), block 256, 48 KB LDS.
// ---------------------------------------------------------------------------
__global__ __launch_bounds__(256)
void proj_qkv(const f16* __restrict__ xq, const f16* __restrict__ xk,
              const f16* __restrict__ xv, const f16* __restrict__ wq,
              const f16* __restrict__ wk, const f16* __restrict__ wv,
              const float* __restrict__ bq, const float* __restrict__ bk,
              const float* __restrict__ bv, f16* __restrict__ qo,
              f16* __restrict__ ko, f16* __restrict__ vo)
{
    // decode: id = t8 + 8*(o + 4*(which + 3*rhi)), r = rhi*8 + t8
    const int id = blockIdx.x;
    const int t8 = id & 7;
    const int rest = id >> 3;
    const int ob = rest & 3;
    const int rem = rest >> 2;
    const int which = rem % 3;
    const int rhi = rem / 3;
    const int r0 = (rhi * 8 + t8) * 64;    // flat (b,t)
    const int o0 = ob * 128;               // out channel

    const f16* X = (which == 0) ? xq : (which == 1) ? xk : xv;
    const f16* W = (which == 0) ? wq : (which == 1) ? wk : wv;
    const float* bias = (which == 0) ? bq : (which == 1) ? bk : bv;
    const float scale = (which == 0) ? 0.125f * LOG2E : 1.0f;

    const int tid = threadIdx.x;
    const int w = tid >> 6, lane = tid & 63;
    const int quad = lane >> 4, l15 = lane & 15;

    __shared__ __align__(16) f16 Xs[64 * 128];    // 16 KB
    __shared__ __align__(16) f16 Wsh[128 * 128];  // 32 KB

    const int srow = tid >> 4;                    // 0..15 (+16/pass)
    const int scol = ((tid & 15) ^ srow) << 3;    // pre-swizzled global col

    const f16* Xg = X + (size_t)(r0 + srow) * CCH + scol;
    const f16* Wg = W + (size_t)(o0 + srow) * CCH + scol;

    const int ax = (which < 2) ? (w >> 1) : (w & 1);
    const int aw = (which < 2) ? (w & 1) : (w >> 1);

    f32x4 acc[8] = {};

    for (int kc = 0; kc < 4; ++kc) {
        if (kc) __syncthreads();
        const int c1 = kc * 128;
        #pragma unroll
        for (int jj = 0; jj < 8; ++jj)
            dma16(Wg + c1 + (size_t)(16 * jj) * CCH, &Wsh[((size_t)tid + 256 * jj) * 8]);
        #pragma unroll
        for (int jj = 0; jj < 4; ++jj)
            dma16(Xg + c1 + (size_t)(16 * jj) * CCH, &Xs[((size_t)tid + 256 * jj) * 8]);
        __syncthreads();

        #pragma unroll
        for (int ks = 0; ks < 4; ++ks) {
            const int sl = ((ks * 4 + quad) ^ l15) << 3;
            f16x8 xf[2], wf[4];
            #pragma unroll
            for (int i = 0; i < 2; ++i)
                xf[i] = *(const f16x8*)&Xs[(32 * ax + 16 * i + l15) * 128 + sl];
            #pragma unroll
            for (int j = 0; j < 4; ++j)
                wf[j] = *(const f16x8*)&Wsh[(64 * aw + 16 * j + l15) * 128 + sl];
            if (which < 2) {
                #pragma unroll
                for (int i = 0; i < 2; ++i)
                    #pragma unroll
                    for (int j = 0; j < 4; ++j)
                        acc[i * 4 + j] = __builtin_amdgcn_mfma_f32_16x16x32_f16(
                            xf[i], wf[j], acc[i * 4 + j], 0, 0, 0);
            } else {
                #pragma unroll
                for (int i = 0; i < 4; ++i)
                    #pragma unroll
                    for (int j = 0; j < 2; ++j)
                        acc[i * 2 + j] = __builtin_amdgcn_mfma_f32_16x16x32_f16(
                            wf[i], xf[j], acc[i * 2 + j], 0, 0, 0);
            }
        }
    }

    if (which < 2) {
        f16* out = (which == 0) ? qo : ko;
        float bl[4];
        #pragma unroll
        for (int j = 0; j < 4; ++j) bl[j] = bias[o0 + 64 * aw + 16 * j + l15];
        #pragma unroll
        for (int i = 0; i < 2; ++i)
            #pragma unroll
            for (int r = 0; r < 4; ++r) {
                size_t row = (size_t)(r0 + 32 * ax + 16 * i + 4 * quad + r) * CCH;
                #pragma unroll
                for (int j = 0; j < 4; ++j)
                    out[row + o0 + 64 * aw + 16 * j + l15] =
                        (f16)((acc[i * 4 + j][r] + bl[j]) * scale);
            }
    } else {
        const int bb = r0 >> 10, tb = r0 & 1023;
        #pragma unroll
        for (int i = 0; i < 4; ++i) {
            float4 bv4 = *(const float4*)&bias[o0 + 64 * aw + 16 * i + 4 * quad];
            float bl[4] = {bv4.x, bv4.y, bv4.z, bv4.w};
            #pragma unroll
            for (int r = 0; r < 4; ++r) {
                size_t row = ((size_t)(bb * CCH + o0 + 64 * aw + 16 * i + 4 * quad + r)) * T_LEN;
                #pragma unroll
                for (int j = 0; j < 2; ++j)
                    vo[row + tb + 32 * ax + 16 * j + l15] =
                        (f16)(acc[i * 2 + j][r] + bl[r]);
            }
        }
    }
}

// ---------------------------------------------------------------------------
// MFMA flash attention — R11 (8-wave split-s, dbuf K/V, wave-private Ps,
// ones-MFMA row-sum, raw v_exp_f32 + cvt_pkrtz, XCD-grouped 1-D grid).
// (unchanged)
// ---------------------------------------------------------------------------
__global__ __launch_bounds__(512, 4)
void attn_mfma(const f16* __restrict__ q, const f16* __restrict__ kk,
               const f16* __restrict__ v, const float* __restrict__ ekg,
               const float* __restrict__ evg, f16* __restrict__ ctx)
{
    const int G = gridDim.x >> 4;                  // NH*B groups
    const int grp = blockIdx.x % G;                // (b,h) group -> XCD grp%8
    const int ib = blockIdx.x / G;                 // t-block 0..15
    const int h = grp & 7, b = grp >> 3;
    const int t0 = ib * 64;
    const int tid = threadIdx.x;
    const int w = tid >> 6, lane = tid & 63;
    const int quad = lane >> 4, l15 = lane & 15;
    const int qw = w & 3, sw = w >> 2;

    __shared__ __align__(16) f16 Qs[4096], Ps[4096];
    __shared__ __align__(16) f16 KV[2][2][4096];   // [buf][0=K,1=V][64x64 swz]
    __shared__ float eks[576], evs[576];
    __shared__ float lsp[2][64];

    const int srow = tid >> 3;                     // 0..63
    const int scol = ((tid & 7) ^ (srow & 7)) << 3;

    for (int i = tid; i < 576; i += 512) {
        eks[i] = ekg[h * 576 + i];
        evs[i] = evg[h * 576 + i];
    }

    const f16* gk = kk + ((size_t)(b * T_LEN + srow)) * CCH + h * DH + scol;
    const f16* gv = v + ((size_t)(b * CCH + h * DH + srow)) * T_LEN + scol;

    dma16(q + ((size_t)(b * T_LEN + t0 + srow)) * CCH + h * DH + scol, &Qs[(size_t)tid * 8]);
    dma16(gk, &KV[0][0][(size_t)tid * 8]);
    dma16(gv, &KV[0][1][(size_t)tid * 8]);
    __syncthreads();

    f16x8 qf[2];
    #pragma unroll
    for (int ks = 0; ks < 2; ++ks)
        qf[ks] = *(const f16x8*)&Qs[(16 * qw + l15) * 64 + (((ks * 4 + quad) ^ (l15 & 7)) << 3)];

    const f16 one_h = (f16)1.f;
    f16x8 onesf = {one_h, one_h, one_h, one_h, one_h, one_h, one_h, one_h};

    const int myt = 16 * qw + l15;
    // loop-invariant Ps store addresses (ct = 2sw+cti -> 2*ct = 4sw+2cti)
    const int colh0 = (((4 * sw + (quad >> 1)) ^ (myt & 7)) << 3) + (quad & 1) * 4;
    const int colh1 = (((4 * sw + 2 + (quad >> 1)) ^ (myt & 7)) << 3) + (quad & 1) * 4;

    f32x4 Sacc = {};                   // row-sum accum, rows t_loc=16qw+4quad+r
    f32x4 O[4] = {};

    const bool corner_hi = (ib == 0);
    const bool corner_lo = (ib == 15);

    for (int it = 0; it < 16; ++it) {
        const int kb = it, cb = it & 1;
        if (it) __syncthreads();

        if (it < 15) {
            const int nb = cb ^ 1;
            dma16(gk + (size_t)((it + 1) * 64) * CCH, &KV[nb][0][(size_t)tid * 8]);
            dma16(gv + (it + 1) * 64, &KV[nb][1][(size_t)tid * 8]);
        }

        f32x4 S[2] = {};
        __builtin_amdgcn_s_setprio(1);
        #pragma unroll
        for (int ks = 0; ks < 2; ++ks) {
            #pragma unroll
            for (int cti = 0; cti < 2; ++cti) {
                const int ct = 2 * sw + cti;
                f16x8 aa = *(const f16x8*)&KV[cb][0][(16 * ct + l15) * 64 +
                                                     (((ks * 4 + quad) ^ (l15 & 7)) << 3)];
                S[cti] = __builtin_amdgcn_mfma_f32_16x16x32_f16(aa, qf[ks], S[cti], 0, 0, 0);
            }
        }
        __builtin_amdgcn_s_setprio(0);

        if ((corner_hi && kb == 15) || (corner_lo && kb == 0)) {
            const int s0g = kb * 64;
            #pragma unroll
            for (int cti = 0; cti < 2; ++cti) {
                const int ct = 2 * sw + cti;
                #pragma unroll
                for (int r = 0; r < 4; ++r) {
                    int t_g = t0 + myt;
                    int s_g = s0g + 16 * ct + 4 * quad + r;
                    int df = s_g - t_g;
                    if (df >= 1019 && df <= 1023) {
                        const float* ekp = &eks[(df - 1019) * 64];
                        float sacc = 0.f;
                        for (int d = 0; d < 64; ++d)
                            sacc += (float)Qs[myt * 64 + (((d >> 3) ^ (myt & 7)) << 3) + (d & 7)] * ekp[d];
                        S[cti][r] += sacc;
                    } else if (df >= -1023 && df <= -1021) {
                        const float* ekp = &eks[(1029 + df) * 64];
                        const int t2 = myt - 1;
                        float sacc = 0.f;
                        for (int d = 0; d < 64; ++d)
                            sacc += (float)Qs[t2 * 64 + (((d >> 3) ^ (t2 & 7)) << 3) + (d & 7)] * ekp[d];
                        S[cti][r] += sacc;
                    }
                }
            }
        }

        {
            // cti = 0
            h16x2 plo = __builtin_amdgcn_cvt_pkrtz(EXP2(S[0][0]), EXP2(S[0][1]));
            h16x2 phi = __builtin_amdgcn_cvt_pkrtz(EXP2(S[0][2]), EXP2(S[0][3]));
            f16x4 pk_;
            pk_[0] = (f16)plo[0]; pk_[1] = (f16)plo[1];
            pk_[2] = (f16)phi[0]; pk_[3] = (f16)phi[1];
            *(f16x4*)&Ps[myt * 64 + colh0] = pk_;
            // cti = 1
            plo = __builtin_amdgcn_cvt_pkrtz(EXP2(S[1][0]), EXP2(S[1][1]));
            phi = __builtin_amdgcn_cvt_pkrtz(EXP2(S[1][2]), EXP2(S[1][3]));
            pk_[0] = (f16)plo[0]; pk_[1] = (f16)plo[1];
            pk_[2] = (f16)phi[0]; pk_[3] = (f16)phi[1];
            *(f16x4*)&Ps[myt * 64 + colh1] = pk_;
        }
        // no barrier: Ps quarter (rows 16qw..+15, cols 32sw..+31) wave-private.

        __builtin_amdgcn_s_setprio(1);
        {
            f16x8 aa = *(const f16x8*)&Ps[(16 * qw + l15) * 64 +
                                          (((sw * 4 + quad) ^ (l15 & 7)) << 3)];
            #pragma unroll
            for (int ct = 0; ct < 4; ++ct) {
                f16x8 bf = *(const f16x8*)&KV[cb][1][(16 * ct + l15) * 64 +
                                                     (((sw * 4 + quad) ^ (l15 & 7)) << 3)];
                O[ct] = __builtin_amdgcn_mfma_f32_16x16x32_f16(aa, bf, O[ct], 0, 0, 0);
            }
            // row-sum on the MFMA pipe: B==1 -> every D col = sum_k P[row][k]
            Sacc = __builtin_amdgcn_mfma_f32_16x16x32_f16(aa, onesf, Sacc, 0, 0, 0);
        }
        __builtin_amdgcn_s_setprio(0);

        const int s0g = kb * 64;
        if (s0g <= t0 + 67 && s0g + 63 >= t0 - 4) {
            #pragma unroll
            for (int r = 0; r < 4; ++r) {
                int t_loc = 16 * qw + 4 * quad + r;
                int t_g = t0 + t_loc;
                int slo = max(max(s0g, t_g - 4), s0g + 32 * sw);
                int shi = min(min(s0g + 63, t_g + 4), s0g + 32 * sw + 31);
                for (int s = slo; s <= shi; ++s) {
                    int sl = s - s0g;
                    float p = (float)Ps[t_loc * 64 + (((sl >> 3) ^ (t_loc & 7)) << 3) + (sl & 7)];
                    const float* evp = &evs[(s - t_g + 4) * 64];
                    #pragma unroll
                    for (int ct = 0; ct < 4; ++ct)
                        O[ct][r] += p * evp[16 * ct + l15];
                }
            }
        }
    }

    // ---- cross-sw reduction ----
    if (l15 == 0) {
        #pragma unroll
        for (int r = 0; r < 4; ++r)
            lsp[sw][16 * qw + 4 * quad + r] = Sacc[r];
    }
    __syncthreads();                       // all K/V reads done; lsp visible

    float* Ored = (float*)&KV[0][0][0];    // 64 rows x stride 66 = 16.9 KB
    if (sw == 1) {
        #pragma unroll
        for (int r = 0; r < 4; ++r) {
            const int t_loc = 16 * qw + 4 * quad + r;
            #pragma unroll
            for (int ct = 0; ct < 4; ++ct)
                Ored[t_loc * 66 + 16 * ct + l15] = O[ct][r];
        }
    }
    __syncthreads();

    if (sw == 0) {
        #pragma unroll
        for (int r = 0; r < 4; ++r) {
            const int t_loc = 16 * qw + 4 * quad + r;
            const float rl = 1.0f / (lsp[0][t_loc] + lsp[1][t_loc]);
            size_t rowo = ((size_t)(b * T_LEN + t0 + t_loc)) * CCH + h * DH;
            #pragma unroll
            for (int ct = 0; ct < 4; ++ct)
                ctx[rowo + 16 * ct + l15] =
                    (f16)((O[ct][r] + Ored[t_loc * 66 + 16 * ct + l15]) * rl);
        }
    }
}

// ---------------------------------------------------------------------------
// output projection 64(o) x 64(t), BK=128, XCD-aware 1-D grid: id%8 == r%8,
// so all 8 o-tiles of one ctx row-panel share an XCD L2 (panel 64 KB + Wo
// 512 KB per XCD). Math identical to R11. grid(B*128), block 256, 32 KB LDS.
// ---------------------------------------------------------------------------
__global__ __launch_bounds__(256)
void proj_out(const f16* __restrict__ ctx, const f16* __restrict__ Wo,
              const float* __restrict__ bo, float* __restrict__ out)
{
    // decode: id = t8 + 8*(o + 8*rhi), r = rhi*8 + t8
    const int id = blockIdx.x;
    const int t8 = id & 7;
    const int rest = id >> 3;
    const int ob = rest & 7;
    const int rhi = rest >> 3;
    const int r0 = (rhi * 8 + t8) * 64;    // flat (b,t)
    const int o0 = ob * 64;

    const int tid = threadIdx.x;
    const int w = tid >> 6, lane = tid & 63;
    const int quad = lane >> 4, l15 = lane & 15;
    const int a  = w >> 1;   // o-half (32 rows)
    const int b2 = w & 1;    // t-half (32 cols)

    __shared__ __align__(16) f16 Cs[64 * 128];    // 16 KB
    __shared__ __align__(16) f16 Wsh[64 * 128];   // 16 KB

    const int srow = tid >> 4;                    // 0..15 (+16/pass)
    const int scol = ((tid & 15) ^ srow) << 3;

    const f16* Cg = ctx + (size_t)(r0 + srow) * CCH + scol;
    const f16* Wg = Wo + (size_t)(o0 + srow) * CCH + scol;

    f32x4 acc[2][2] = {};

    for (int kc = 0; kc < 4; ++kc) {
        if (kc) __syncthreads();
        const int c1 = kc * 128;
        #pragma unroll
        for (int jj = 0; jj < 4; ++jj) {
            dma16(Wg + c1 + (size_t)(16 * jj) * CCH, &Wsh[((size_t)tid + 256 * jj) * 8]);
            dma16(Cg + c1 + (size_t)(16 * jj) * CCH, &Cs[((size_t)tid + 256 * jj) * 8]);
        }
        __syncthreads();

        #pragma unroll
        for (int ks = 0; ks < 4; ++ks) {
            const int sl = ((ks * 4 + quad) ^ l15) << 3;
            f16x8 wf[2], cf[2];
            #pragma unroll
            for (int i = 0; i < 2; ++i)
                wf[i] = *(const f16x8*)&Wsh[(32 * a + 16 * i + l15) * 128 + sl];
            #pragma unroll
            for (int j = 0; j < 2; ++j)
                cf[j] = *(const f16x8*)&Cs[(32 * b2 + 16 * j + l15) * 128 + sl];
            #pragma unroll
            for (int i = 0; i < 2; ++i)
                #pragma unroll
                for (int j = 0; j < 2; ++j)
                    acc[i][j] = __builtin_amdgcn_mfma_f32_16x16x32_f16(
                        wf[i], cf[j], acc[i][j], 0, 0, 0);
        }
    }

    const int bb = r0 >> 10, tb = r0 & 1023;
    #pragma unroll
    for (int i = 0; i < 2; ++i) {
        float4 bv4 = *(const float4*)&bo[o0 + 32 * a + 16 * i + 4 * quad];
        float bl[4] = {bv4.x, bv4.y, bv4.z, bv4.w};
        #pragma unroll
        for (int r = 0; r < 4; ++r) {
            size_t row = ((size_t)(bb * CCH + o0 + 32 * a + 16 * i + 4 * quad + r)) * T_LEN;
            #pragma unroll
            for (int j = 0; j < 2; ++j)
                out[row + tb + 32 * b2 + 16 * j + l15] = acc[i][j][r] + bl[r];
        }
    }
}

// ---------------------------------------------------------------------------
extern "C" void kernel_launch(void* const* d_in, const int* in_sizes, int n_in,
                              void* d_out, int out_size, void* d_ws, size_t ws_size,
                              hipStream_t stream)
{
    const float* x_q = (const float*)d_in[0];
    const float* x_k = (const float*)d_in[1];
    const float* x_v = (const float*)d_in[2];
    const float* Wq  = (const float*)d_in[3];
    const float* bq  = (const float*)d_in[4];
    const float* Wk  = (const float*)d_in[5];
    const float* bk  = (const float*)d_in[6];
    const float* Wv  = (const float*)d_in[7];
    const float* bv  = (const float*)d_in[8];
    const float* Wo  = (const float*)d_in[9];
    const float* bo  = (const float*)d_in[10];
    const float* erk = (const float*)d_in[11];
    const float* erv = (const float*)d_in[12];

    const int B = in_sizes[0] / (CCH * T_LEN);
    const size_t te = (size_t)B * CCH * T_LEN;
    const size_t we = (size_t)CCH * CCH;

    f16* p = (f16*)d_ws;
    f16* xTq = p; p += te;
    f16* xTk = p; p += te;
    f16* xTv = p; p += te;
    f16* wqh = p; p += we;
    f16* wkh = p; p += we;
    f16* wvh = p; p += we;
    f16* woh = p; p += we;
    f16* qh  = p; p += te;
    f16* kh  = p; p += te;
    f16* vh  = p; p += te;
    f16* ch  = p; p += te;

    dim3 blk(256);
    prep_kernel<<<dim3(16, 8, 3 * B + 8), blk, 0, stream>>>(
        x_q, x_k, x_v, Wq, Wk, Wv, Wo, xTq, xTk, xTv, wqh, wkh, wvh, woh, B);
    proj_qkv<<<dim3(B * 192), blk, 0, stream>>>(
        xTq, xTk, xTv, wqh, wkh, wvh, bq, bk, bv, qh, kh, vh);
    attn_mfma<<<dim3(16 * NH * B), dim3(512), 0, stream>>>(
        qh, kh, vh, erk, erv, ch);
    proj_out<<<dim3(B * 128), blk, 0, stream>>>(
        ch, woh, bo, (float*)d_out);
}